// Round 1
// baseline (881.067 us; speedup 1.0000x reference)
//
#include <hip/hip_runtime.h>
#include <hip/hip_bf16.h>
#include <cstdint>

// Problem dims (compile-time)
constexpr int B_ = 4, H_ = 16, S_ = 1024, D_ = 1024, DK_ = 64;
// rows r = s*B+b for [S,B,D] tensors; r = b*S+s for [B,S,D] tensors

// ---------------------------------------------------------------------------
// Projection GEMM: Y[b,h,s,t] = sum_d X[s,b,d] * W[h*64+t, d]
// X is [S,B,D] (natural q/k/v layout). Row index r = s*B+b is the flat row.
// 64x64 tile, 256 threads, 4x4 per thread, K-tile 16.
// ---------------------------------------------------------------------------
__global__ __launch_bounds__(256) void k_proj(const float* __restrict__ X,
                                              const float* __restrict__ W,
                                              float* __restrict__ Y) {
  __shared__ float As[16][68];
  __shared__ float Bs[16][68];
  const int tid = threadIdx.x;
  const int rt = blockIdx.x, ct = blockIdx.y;
  const int lm = tid >> 2;           // 0..63 row-in-tile for loads
  const int lk = (tid & 3) << 2;     // 0,4,8,12 k-offset (float4)
  const float* Xr = X + (size_t)(rt * 64 + lm) * D_;
  const float* Wr = W + (size_t)(ct * 64 + lm) * D_;
  const int ty = tid >> 4, tx = tid & 15;
  float acc[4][4] = {};
  for (int k0 = 0; k0 < D_; k0 += 16) {
    const float4 a = *(const float4*)(Xr + k0 + lk);
    const float4 w = *(const float4*)(Wr + k0 + lk);
    As[lk + 0][lm] = a.x; As[lk + 1][lm] = a.y; As[lk + 2][lm] = a.z; As[lk + 3][lm] = a.w;
    Bs[lk + 0][lm] = w.x; Bs[lk + 1][lm] = w.y; Bs[lk + 2][lm] = w.z; Bs[lk + 3][lm] = w.w;
    __syncthreads();
#pragma unroll
    for (int kk = 0; kk < 16; ++kk) {
      const float4 av = *(const float4*)&As[kk][ty << 2];
      const float4 bv = *(const float4*)&Bs[kk][tx << 2];
      const float aa[4] = {av.x, av.y, av.z, av.w};
      const float bb[4] = {bv.x, bv.y, bv.z, bv.w};
#pragma unroll
      for (int i = 0; i < 4; ++i)
#pragma unroll
        for (int j = 0; j < 4; ++j) acc[i][j] = fmaf(aa[i], bb[j], acc[i][j]);
    }
    __syncthreads();
  }
  // write: head h == ct (64-wide col tile aligns with head), t = tx*4+j
#pragma unroll
  for (int i = 0; i < 4; ++i) {
    const int r = rt * 64 + (ty << 2) + i;
    const int s = r >> 2;   // r / B
    const int b = r & 3;    // r % B
    float* yp = Y + (((size_t)(b * H_ + ct) * S_) + s) * DK_ + (tx << 2);
    const float4 o4 = {acc[i][0], acc[i][1], acc[i][2], acc[i][3]};
    *(float4*)yp = o4;
  }
}

// ---------------------------------------------------------------------------
// Logits: P[bh,i,j] = (sum_t Qh[bh,i,t]*Kh[bh,j,t]) / 8 * sph[bh,i,j]
// Written straight into d_out's p_attn region (softmaxed in-place next).
// ---------------------------------------------------------------------------
__global__ __launch_bounds__(256) void k_logits(const float* __restrict__ Qh,
                                                const float* __restrict__ Kh,
                                                const float* __restrict__ sph,
                                                float* __restrict__ P) {
  __shared__ float As[16][68];
  __shared__ float Bs[16][68];
  const int tid = threadIdx.x;
  const int it = blockIdx.x, jt = blockIdx.y, bh = blockIdx.z;
  const int lm = tid >> 2, lk = (tid & 3) << 2;
  const float* Qr = Qh + (size_t)bh * S_ * DK_ + (size_t)(it * 64 + lm) * DK_;
  const float* Kr = Kh + (size_t)bh * S_ * DK_ + (size_t)(jt * 64 + lm) * DK_;
  const int ty = tid >> 4, tx = tid & 15;
  float acc[4][4] = {};
  for (int k0 = 0; k0 < DK_; k0 += 16) {
    const float4 a = *(const float4*)(Qr + k0 + lk);
    const float4 w = *(const float4*)(Kr + k0 + lk);
    As[lk + 0][lm] = a.x; As[lk + 1][lm] = a.y; As[lk + 2][lm] = a.z; As[lk + 3][lm] = a.w;
    Bs[lk + 0][lm] = w.x; Bs[lk + 1][lm] = w.y; Bs[lk + 2][lm] = w.z; Bs[lk + 3][lm] = w.w;
    __syncthreads();
#pragma unroll
    for (int kk = 0; kk < 16; ++kk) {
      const float4 av = *(const float4*)&As[kk][ty << 2];
      const float4 bv = *(const float4*)&Bs[kk][tx << 2];
      const float aa[4] = {av.x, av.y, av.z, av.w};
      const float bb[4] = {bv.x, bv.y, bv.z, bv.w};
#pragma unroll
      for (int i = 0; i < 4; ++i)
#pragma unroll
        for (int j = 0; j < 4; ++j) acc[i][j] = fmaf(aa[i], bb[j], acc[i][j]);
    }
    __syncthreads();
  }
  const size_t pbase = (size_t)bh * S_ * S_;
#pragma unroll
  for (int i = 0; i < 4; ++i) {
    const int gi = it * 64 + (ty << 2) + i;
    const int gj = jt * 64 + (tx << 2);
    const size_t idx = pbase + (size_t)gi * S_ + gj;
    const float4 sv = *(const float4*)(sph + idx);
    const float4 o4 = {acc[i][0] * 0.125f * sv.x, acc[i][1] * 0.125f * sv.y,
                       acc[i][2] * 0.125f * sv.z, acc[i][3] * 0.125f * sv.w};
    *(float4*)(P + idx) = o4;
  }
}

// ---------------------------------------------------------------------------
// Row softmax, in place. One block (256 thr) per row of 1024.
// ---------------------------------------------------------------------------
__global__ __launch_bounds__(256) void k_softmax(float* __restrict__ P) {
  const size_t base = (size_t)blockIdx.x * S_;
  const int tid = threadIdx.x;
  const float4 x = *(const float4*)(P + base + (tid << 2));
  float m = fmaxf(fmaxf(x.x, x.y), fmaxf(x.z, x.w));
#pragma unroll
  for (int off = 1; off < 64; off <<= 1) m = fmaxf(m, __shfl_xor(m, off));
  __shared__ float rmax[4];
  __shared__ float rsum[4];
  const int wv = tid >> 6, ln = tid & 63;
  if (ln == 0) rmax[wv] = m;
  __syncthreads();
  m = fmaxf(fmaxf(rmax[0], rmax[1]), fmaxf(rmax[2], rmax[3]));
  float4 e;
  e.x = expf(x.x - m); e.y = expf(x.y - m); e.z = expf(x.z - m); e.w = expf(x.w - m);
  float s = e.x + e.y + e.z + e.w;
#pragma unroll
  for (int off = 1; off < 64; off <<= 1) s += __shfl_xor(s, off);
  if (ln == 0) rsum[wv] = s;
  __syncthreads();
  const float inv = 1.0f / (rsum[0] + rsum[1] + rsum[2] + rsum[3]);
  const float4 o = {e.x * inv, e.y * inv, e.z * inv, e.w * inv};
  *(float4*)(P + base + (tid << 2)) = o;
}

// ---------------------------------------------------------------------------
// PV: O[b, i, h*64+t] = sum_j P[bh,i,j] * Vh[bh,j,t].  O is [B,S,D].
// ---------------------------------------------------------------------------
__global__ __launch_bounds__(256) void k_pv(const float* __restrict__ P,
                                            const float* __restrict__ Vh,
                                            float* __restrict__ O) {
  __shared__ float As[16][68];  // P[i][j-slice]
  __shared__ float Bs[16][68];  // V[j-slice][t]
  const int tid = threadIdx.x;
  const int it = blockIdx.x, bh = blockIdx.z;
  const int b = bh >> 4, h = bh & 15;
  const int lm = tid >> 2, lk = (tid & 3) << 2;
  const float* Pr = P + (size_t)bh * S_ * S_ + (size_t)(it * 64 + lm) * S_;
  const float* Vb = Vh + (size_t)bh * S_ * DK_;
  const int jm = tid >> 4, tt = (tid & 15) << 2;
  const int ty = tid >> 4, tx = tid & 15;
  float acc[4][4] = {};
  for (int k0 = 0; k0 < S_; k0 += 16) {
    const float4 a = *(const float4*)(Pr + k0 + lk);
    const float4 v = *(const float4*)(Vb + (size_t)(k0 + jm) * DK_ + tt);
    As[lk + 0][lm] = a.x; As[lk + 1][lm] = a.y; As[lk + 2][lm] = a.z; As[lk + 3][lm] = a.w;
    *(float4*)&Bs[jm][tt] = v;
    __syncthreads();
#pragma unroll
    for (int kk = 0; kk < 16; ++kk) {
      const float4 av = *(const float4*)&As[kk][ty << 2];
      const float4 bv = *(const float4*)&Bs[kk][tx << 2];
      const float aa[4] = {av.x, av.y, av.z, av.w};
      const float bb[4] = {bv.x, bv.y, bv.z, bv.w};
#pragma unroll
      for (int i = 0; i < 4; ++i)
#pragma unroll
        for (int j = 0; j < 4; ++j) acc[i][j] = fmaf(aa[i], bb[j], acc[i][j]);
    }
    __syncthreads();
  }
#pragma unroll
  for (int i = 0; i < 4; ++i) {
    const int gi = it * 64 + (ty << 2) + i;
    float* op = O + (size_t)(b * S_ + gi) * D_ + h * DK_ + (tx << 2);
    const float4 o4 = {acc[i][0], acc[i][1], acc[i][2], acc[i][3]};
    *(float4*)op = o4;
  }
}

// ---------------------------------------------------------------------------
// Wo GEMM + residual: Z[b,s,o] = sum_d O[b,s,d]*Wo[o,d] + q[s,b,o]
// Row r = b*S+s (O is [B,S,D]).
// ---------------------------------------------------------------------------
__global__ __launch_bounds__(256) void k_wo(const float* __restrict__ O,
                                            const float* __restrict__ W,
                                            const float* __restrict__ q,
                                            float* __restrict__ Z) {
  __shared__ float As[16][68];
  __shared__ float Bs[16][68];
  const int tid = threadIdx.x;
  const int rt = blockIdx.x, ct = blockIdx.y;
  const int lm = tid >> 2, lk = (tid & 3) << 2;
  const float* Or = O + (size_t)(rt * 64 + lm) * D_;
  const float* Wr = W + (size_t)(ct * 64 + lm) * D_;
  const int ty = tid >> 4, tx = tid & 15;
  float acc[4][4] = {};
  for (int k0 = 0; k0 < D_; k0 += 16) {
    const float4 a = *(const float4*)(Or + k0 + lk);
    const float4 w = *(const float4*)(Wr + k0 + lk);
    As[lk + 0][lm] = a.x; As[lk + 1][lm] = a.y; As[lk + 2][lm] = a.z; As[lk + 3][lm] = a.w;
    Bs[lk + 0][lm] = w.x; Bs[lk + 1][lm] = w.y; Bs[lk + 2][lm] = w.z; Bs[lk + 3][lm] = w.w;
    __syncthreads();
#pragma unroll
    for (int kk = 0; kk < 16; ++kk) {
      const float4 av = *(const float4*)&As[kk][ty << 2];
      const float4 bv = *(const float4*)&Bs[kk][tx << 2];
      const float aa[4] = {av.x, av.y, av.z, av.w};
      const float bb[4] = {bv.x, bv.y, bv.z, bv.w};
#pragma unroll
      for (int i = 0; i < 4; ++i)
#pragma unroll
        for (int j = 0; j < 4; ++j) acc[i][j] = fmaf(aa[i], bb[j], acc[i][j]);
    }
    __syncthreads();
  }
#pragma unroll
  for (int i = 0; i < 4; ++i) {
    const int r = rt * 64 + (ty << 2) + i;
    const int b = r >> 10, s = r & 1023;
    const int o = ct * 64 + (tx << 2);
    const float4 rv = *(const float4*)(q + (size_t)(s * B_ + b) * D_ + o);
    const float4 o4 = {acc[i][0] + rv.x, acc[i][1] + rv.y, acc[i][2] + rv.z, acc[i][3] + rv.w};
    *(float4*)(Z + (size_t)r * D_ + o) = o4;
  }
}

// ---------------------------------------------------------------------------
// LayerNorm over D, output swapped back to [S,B,D].
// ---------------------------------------------------------------------------
__global__ __launch_bounds__(256) void k_ln(const float* __restrict__ Z,
                                            const float* __restrict__ gamma,
                                            const float* __restrict__ beta,
                                            float* __restrict__ out) {
  const int r = blockIdx.x;          // b*S+s
  const int b = r >> 10, s = r & 1023;
  const int tid = threadIdx.x;
  const float4 z = *(const float4*)(Z + (size_t)r * D_ + (tid << 2));
  float sum = z.x + z.y + z.z + z.w;
  float sq = z.x * z.x + z.y * z.y + z.z * z.z + z.w * z.w;
#pragma unroll
  for (int off = 1; off < 64; off <<= 1) {
    sum += __shfl_xor(sum, off);
    sq += __shfl_xor(sq, off);
  }
  __shared__ float rs[4];
  __shared__ float rq[4];
  const int wv = tid >> 6, ln = tid & 63;
  if (ln == 0) { rs[wv] = sum; rq[wv] = sq; }
  __syncthreads();
  const float tsum = rs[0] + rs[1] + rs[2] + rs[3];
  const float tsq = rq[0] + rq[1] + rq[2] + rq[3];
  const float mu = tsum * (1.0f / 1024.0f);
  const float var = tsq * (1.0f / 1024.0f) - mu * mu;
  const float rstd = rsqrtf(var + 1e-6f);
  const float4 g = *(const float4*)(gamma + (tid << 2));
  const float4 bt = *(const float4*)(beta + (tid << 2));
  float4 o;
  o.x = (z.x - mu) * rstd * g.x + bt.x;
  o.y = (z.y - mu) * rstd * g.y + bt.y;
  o.z = (z.z - mu) * rstd * g.z + bt.z;
  o.w = (z.w - mu) * rstd * g.w + bt.w;
  *(float4*)(out + (size_t)(s * B_ + b) * D_ + (tid << 2)) = o;
}

extern "C" void kernel_launch(void* const* d_in, const int* in_sizes, int n_in,
                              void* d_out, int out_size, void* d_ws, size_t ws_size,
                              hipStream_t stream) {
  const float* q     = (const float*)d_in[0];
  const float* k     = (const float*)d_in[1];
  const float* v     = (const float*)d_in[2];
  const float* sph   = (const float*)d_in[3];
  const float* Wq    = (const float*)d_in[4];
  const float* Wk    = (const float*)d_in[5];
  const float* Wv    = (const float*)d_in[6];
  const float* Wv_o  = (const float*)d_in[7];
  const float* gamma = (const float*)d_in[8];
  const float* beta  = (const float*)d_in[9];

  float* out = (float*)d_out;                       // [S,B,D] LN output
  float* P = out + (size_t)4 * 1024 * 1024;         // p_attn region [B,H,S,S]

  float* ws = (float*)d_ws;                          // 80 MiB used
  float* Qh = ws;                                    // [B,H,S,DK]
  float* Kh = Qh + (size_t)4194304;
  float* Vh = Kh + (size_t)4194304;
  float* O  = Vh + (size_t)4194304;                  // [B,S,D]
  float* Z  = O + (size_t)4194304;                   // [B,S,D]

  const dim3 blk(256);
  k_proj<<<dim3(64, 16), blk, 0, stream>>>(q, Wq, Qh);
  k_proj<<<dim3(64, 16), blk, 0, stream>>>(k, Wk, Kh);
  k_proj<<<dim3(64, 16), blk, 0, stream>>>(v, Wv, Vh);
  k_logits<<<dim3(16, 16, 64), blk, 0, stream>>>(Qh, Kh, sph, P);
  k_softmax<<<dim3(65536), blk, 0, stream>>>(P);
  k_pv<<<dim3(16, 1, 64), blk, 0, stream>>>(P, Vh, O);
  k_wo<<<dim3(64, 16), blk, 0, stream>>>(O, Wv_o, q, Z);
  k_ln<<<dim3(4096), blk, 0, stream>>>(Z, gamma, beta, out);
}

// Round 3
// 313.736 us; speedup vs baseline: 2.8083x; 2.8083x over previous
//
#include <hip/hip_runtime.h>
#include <hip/hip_bf16.h>
#include <hip/hip_fp16.h>
#include <cstdint>

// Dims
constexpr int B_ = 4, H_ = 16, S_ = 1024, D_ = 1024, DK_ = 64;

typedef __bf16 bf16x8 __attribute__((ext_vector_type(8)));
typedef float f32x4 __attribute__((ext_vector_type(4)));
#define MFMA16(a, b, c) __builtin_amdgcn_mfma_f32_16x16x32_bf16(a, b, c, 0, 0, 0)

static __device__ inline unsigned short f2bf(float f) {
  __hip_bfloat16 h = __float2bfloat16(f);
  return *reinterpret_cast<unsigned short*>(&h);
}
static __device__ inline unsigned pack_f16(float x, float y) {
  __half hx = __float2half(x), hy = __float2half(y);
  return ((unsigned)(*reinterpret_cast<unsigned short*>(&hy)) << 16) |
         (unsigned)(*reinterpret_cast<unsigned short*>(&hx));
}
static __device__ inline float f16lo(unsigned u) {
  unsigned short s = (unsigned short)(u & 0xffff);
  return __half2float(*reinterpret_cast<__half*>(&s));
}
static __device__ inline float f16hi(unsigned u) {
  unsigned short s = (unsigned short)(u >> 16);
  return __half2float(*reinterpret_cast<__half*>(&s));
}

// ---------------------------------------------------------------------------
// f32 -> bf16 elementwise conversion (vectorized)
// ---------------------------------------------------------------------------
__global__ __launch_bounds__(256) void k_cvt(const float* __restrict__ x,
                                             __hip_bfloat16* __restrict__ y, int n4) {
  const int i = blockIdx.x * 256 + threadIdx.x;
  if (i < n4) {
    const float4 v = reinterpret_cast<const float4*>(x)[i];
    ushort4 o;
    o.x = f2bf(v.x); o.y = f2bf(v.y); o.z = f2bf(v.z); o.w = f2bf(v.w);
    *reinterpret_cast<ushort4*>(&y[(size_t)i * 4]) = o;
  }
}

// ---------------------------------------------------------------------------
// bf16 MFMA GEMM: C[m,t_tile] = A[m, :] . Bw[t, :]   (A 4096x1024, Bw 1024x1024)
// BM=128, BN=64, BK=64, 256 threads (4 waves, 2x2), per wave 64x32 output.
// LDS chunk-XOR swizzle (16B chunks, chunk^=(row&7)) for conflict-floor reads.
// MODE 0: Y bf16 [bh][s][dk], rows m = s*B+b, head = ct
// MODE 1: Y bf16 [bh][dk][s] (transposed; for V)
// MODE 2: Y f32 Z[m][o] = acc + resid[s*B+b][o], rows m = b*S+s
// ---------------------------------------------------------------------------
template <int MODE>
__global__ __launch_bounds__(256) void k_gemm(const __hip_bfloat16* __restrict__ A,
                                              const __hip_bfloat16* __restrict__ Bw,
                                              const float* __restrict__ resid,
                                              __hip_bfloat16* __restrict__ Yb,
                                              float* __restrict__ Yf) {
  __shared__ __hip_bfloat16 Als[128 * 64];
  __shared__ __hip_bfloat16 Bls[64 * 64];
  const int tid = threadIdx.x;
  const int lane = tid & 63;
  const int l15 = lane & 15, g = lane >> 4;
  const int w = tid >> 6;
  const int wr = w >> 1, wc = w & 1;
  const int rt = blockIdx.x, ct = blockIdx.y;
  f32x4 acc[4][2] = {};

  for (int k0 = 0; k0 < D_; k0 += 64) {
    // stage A: 128 rows x 8 chunks(16B); physical chunk p holds logical p^(r&7)
#pragma unroll
    for (int q = 0; q < 4; ++q) {
      const int slot = q * 256 + tid;
      const int r = slot >> 3, p = slot & 7;
      const int lc = p ^ (r & 7);
      const uint4 d = *reinterpret_cast<const uint4*>(
          A + (size_t)(rt * 128 + r) * D_ + k0 + lc * 8);
      *reinterpret_cast<uint4*>(&Als[slot * 8]) = d;
    }
#pragma unroll
    for (int q = 0; q < 2; ++q) {
      const int slot = q * 256 + tid;
      const int r = slot >> 3, p = slot & 7;
      const int lc = p ^ (r & 7);
      const uint4 d = *reinterpret_cast<const uint4*>(
          Bw + (size_t)(ct * 64 + r) * D_ + k0 + lc * 8);
      *reinterpret_cast<uint4*>(&Bls[slot * 8]) = d;
    }
    __syncthreads();
#pragma unroll
    for (int ks = 0; ks < 2; ++ks) {
      bf16x8 bfr[2];
#pragma unroll
      for (int cf = 0; cf < 2; ++cf) {
        const int r = wc * 32 + cf * 16 + l15;
        const int p = (ks * 4 + g) ^ (r & 7);
        bfr[cf] = *reinterpret_cast<const bf16x8*>(&Bls[(r * 8 + p) * 8]);
      }
#pragma unroll
      for (int fi = 0; fi < 4; ++fi) {
        const int r = wr * 64 + fi * 16 + l15;
        const int p = (ks * 4 + g) ^ (r & 7);
        const bf16x8 af = *reinterpret_cast<const bf16x8*>(&Als[(r * 8 + p) * 8]);
        acc[fi][0] = MFMA16(af, bfr[0], acc[fi][0]);
        acc[fi][1] = MFMA16(af, bfr[1], acc[fi][1]);
      }
    }
    __syncthreads();
  }
  // epilogue: D-frag col=l15 (B row t), row=4g+reg (A row m)
#pragma unroll
  for (int fi = 0; fi < 4; ++fi)
#pragma unroll
    for (int cf = 0; cf < 2; ++cf)
#pragma unroll
      for (int r = 0; r < 4; ++r) {
        const int m = rt * 128 + wr * 64 + fi * 16 + 4 * g + r;
        const int t = wc * 32 + cf * 16 + l15;
        const float val = acc[fi][cf][r];
        if (MODE == 0) {
          const int s = m >> 2, b = m & 3;
          Yb[((size_t)((b * H_ + ct) * S_ + s)) * DK_ + t] = __float2bfloat16(val);
        } else if (MODE == 1) {
          const int s = m >> 2, b = m & 3;
          Yb[((size_t)((b * H_ + ct) * DK_ + t)) * S_ + s] = __float2bfloat16(val);
        } else {
          const int b = m >> 10, s = m & 1023;
          const int o = ct * 64 + t;
          Yf[(size_t)m * D_ + o] = val + resid[(size_t)(s * B_ + b) * D_ + o];
        }
      }
}

// ---------------------------------------------------------------------------
// Fused attention: per block = 32 query rows of one (b,h).
// Phase 1: S^T = mfma(K, Q) (swapped so 4 regs = 4 consecutive keys), * sph/8,
//          f16-pack pairs -> LDS [32][512] u32 (pair-index XOR-swizzled).
// Phase 2: row softmax in f32; write normalized P (f32) to d_out; repack rows
//          as bf16 pairs in place.
// Phase 3: O = P.V via mfma(P, V^T-frags); write O bf16 [B][S][D].
// ---------------------------------------------------------------------------
__global__ __launch_bounds__(256) void k_attn(const __hip_bfloat16* __restrict__ Qh,
                                              const __hip_bfloat16* __restrict__ Kh,
                                              const __hip_bfloat16* __restrict__ VT,
                                              const float* __restrict__ sph,
                                              float* __restrict__ Pout,
                                              __hip_bfloat16* __restrict__ O) {
  __shared__ unsigned int Plds[32 * 512];  // 64KB
  const int tid = threadIdx.x, lane = tid & 63, w = tid >> 6;
  const int l15 = lane & 15, g = lane >> 4;
  const int it = blockIdx.x, bh = blockIdx.y;
  const size_t sphbase = ((size_t)bh << 20);

  // ---- phase 1: logits ----
  {
    const int qg = (w >> 1) * 16;      // query sub-block of this wave
    const int kh = (w & 1) * 32;       // key half within each 64-key j-tile
    const int qrow = qg + l15;         // local query row (D-frag col)
    const unsigned sw = (unsigned)((qrow & 7) << 2);
    bf16x8 qf0, qf1;
    {
      const __hip_bfloat16* qp = Qh + ((size_t)bh * S_ + it * 32 + qrow) * DK_ + 8 * g;
      qf0 = *reinterpret_cast<const bf16x8*>(qp);
      qf1 = *reinterpret_cast<const bf16x8*>(qp + 32);
    }
    for (int j = 0; j < 16; ++j) {
      const int key0 = j * 64 + kh;
      const __hip_bfloat16* kp = Kh + ((size_t)bh * S_ + key0 + l15) * DK_ + 8 * g;
      const bf16x8 kf0a = *reinterpret_cast<const bf16x8*>(kp);
      const bf16x8 kf0b = *reinterpret_cast<const bf16x8*>(kp + 32);
      const bf16x8 kf1a = *reinterpret_cast<const bf16x8*>(kp + 16 * DK_);
      const bf16x8 kf1b = *reinterpret_cast<const bf16x8*>(kp + 16 * DK_ + 32);
      f32x4 a0 = {0.f, 0.f, 0.f, 0.f};
      f32x4 a1 = {0.f, 0.f, 0.f, 0.f};
      a0 = MFMA16(kf0a, qf0, a0);
      a0 = MFMA16(kf0b, qf1, a0);
      a1 = MFMA16(kf1a, qf0, a1);
      a1 = MFMA16(kf1b, qf1, a1);
      // sph modulate (4 consecutive keys per reg -> float4)
      const float* sp = sph + sphbase + (((size_t)(it * 32 + qrow)) << 10) + key0 + 4 * g;
      const float4 s0 = *reinterpret_cast<const float4*>(sp);
      const float4 s1 = *reinterpret_cast<const float4*>(sp + 16);
      uint2 u0, u1;
      u0.x = pack_f16(a0[0] * 0.125f * s0.x, a0[1] * 0.125f * s0.y);
      u0.y = pack_f16(a0[2] * 0.125f * s0.z, a0[3] * 0.125f * s0.w);
      u1.x = pack_f16(a1[0] * 0.125f * s1.x, a1[1] * 0.125f * s1.y);
      u1.y = pack_f16(a1[2] * 0.125f * s1.z, a1[3] * 0.125f * s1.w);
      const int base0 = qrow * 512 + (key0 >> 1) + 2 * g;  // pair index
      *reinterpret_cast<uint2*>(&Plds[(unsigned)base0 ^ sw]) = u0;
      *reinterpret_cast<uint2*>(&Plds[(unsigned)(base0 + 8) ^ sw]) = u1;
    }
  }
  __syncthreads();

  // ---- phase 2: softmax (8 rows per wave), write P f32, repack bf16 ----
  for (int rr = 0; rr < 8; ++rr) {
    const int row = w * 8 + rr;
    const unsigned sw = (unsigned)((row & 7) << 2);
    const int lbase = row * 512;
    unsigned uv[8];
    float va[16];
#pragma unroll
    for (int i = 0; i < 8; ++i) {
      uv[i] = Plds[(unsigned)(lbase + lane + 64 * i) ^ sw];
      va[2 * i] = f16lo(uv[i]);
      va[2 * i + 1] = f16hi(uv[i]);
    }
    float m = va[0];
#pragma unroll
    for (int i = 1; i < 16; ++i) m = fmaxf(m, va[i]);
#pragma unroll
    for (int off = 1; off < 64; off <<= 1) m = fmaxf(m, __shfl_xor(m, off));
    float sum = 0.f;
#pragma unroll
    for (int i = 0; i < 16; ++i) {
      va[i] = __expf(va[i] - m);
      sum += va[i];
    }
#pragma unroll
    for (int off = 1; off < 64; off <<= 1) sum += __shfl_xor(sum, off);
    const float inv = 1.f / sum;
    float2* po = reinterpret_cast<float2*>(Pout + ((size_t)bh << 20) +
                                           (((size_t)(it * 32 + row)) << 10));
#pragma unroll
    for (int i = 0; i < 8; ++i) {
      const float p0 = va[2 * i] * inv, p1 = va[2 * i + 1] * inv;
      po[lane + 64 * i] = make_float2(p0, p1);
      Plds[(unsigned)(lbase + lane + 64 * i) ^ sw] =
          ((unsigned)f2bf(p1) << 16) | (unsigned)f2bf(p0);
    }
  }
  __syncthreads();

  // ---- phase 3: PV ----
  {
    const int r0 = (w >> 1) * 16, c0 = (w & 1) * 32;
    const int prow = r0 + l15;
    const unsigned sw = (unsigned)((prow & 7) << 2);
    f32x4 o0 = {0.f, 0.f, 0.f, 0.f};
    f32x4 o1 = {0.f, 0.f, 0.f, 0.f};
    const __hip_bfloat16* vb = VT + (size_t)bh * DK_ * S_ + 8 * g;
#pragma unroll 4
    for (int k0 = 0; k0 < S_; k0 += 32) {
      const bf16x8 pa = *reinterpret_cast<const bf16x8*>(
          &Plds[(unsigned)(prow * 512 + (k0 >> 1) + 4 * g) ^ sw]);
      const bf16x8 vb0 = *reinterpret_cast<const bf16x8*>(vb + (size_t)(c0 + l15) * S_ + k0);
      const bf16x8 vb1 = *reinterpret_cast<const bf16x8*>(vb + (size_t)(c0 + 16 + l15) * S_ + k0);
      o0 = MFMA16(pa, vb0, o0);
      o1 = MFMA16(pa, vb1, o1);
    }
    const int b = bh >> 4, h = bh & 15;
#pragma unroll
    for (int r = 0; r < 4; ++r) {
      const int srow = it * 32 + r0 + 4 * g + r;
      __hip_bfloat16* op = O + ((size_t)(b * S_ + srow)) * D_ + h * DK_;
      op[c0 + l15] = __float2bfloat16(o0[r]);
      op[c0 + 16 + l15] = __float2bfloat16(o1[r]);
    }
  }
}

// ---------------------------------------------------------------------------
// LayerNorm over D, write [S,B,D]
// ---------------------------------------------------------------------------
__global__ __launch_bounds__(256) void k_ln(const float* __restrict__ Z,
                                            const float* __restrict__ gamma,
                                            const float* __restrict__ beta,
                                            float* __restrict__ out) {
  const int r = blockIdx.x;  // b*S+s
  const int b = r >> 10, s = r & 1023;
  const int tid = threadIdx.x;
  const float4 z = *reinterpret_cast<const float4*>(Z + (size_t)r * D_ + (tid << 2));
  float sum = z.x + z.y + z.z + z.w;
  float sq = z.x * z.x + z.y * z.y + z.z * z.z + z.w * z.w;
#pragma unroll
  for (int off = 1; off < 64; off <<= 1) {
    sum += __shfl_xor(sum, off);
    sq += __shfl_xor(sq, off);
  }
  __shared__ float rs[4];
  __shared__ float rq[4];
  const int wv = tid >> 6, ln = tid & 63;
  if (ln == 0) { rs[wv] = sum; rq[wv] = sq; }
  __syncthreads();
  const float tsum = rs[0] + rs[1] + rs[2] + rs[3];
  const float tsq = rq[0] + rq[1] + rq[2] + rq[3];
  const float mu = tsum * (1.0f / 1024.0f);
  const float var = tsq * (1.0f / 1024.0f) - mu * mu;
  const float rstd = rsqrtf(var + 1e-6f);
  const float4 gm = *reinterpret_cast<const float4*>(gamma + (tid << 2));
  const float4 bt = *reinterpret_cast<const float4*>(beta + (tid << 2));
  float4 o;
  o.x = (z.x - mu) * rstd * gm.x + bt.x;
  o.y = (z.y - mu) * rstd * gm.y + bt.y;
  o.z = (z.z - mu) * rstd * gm.z + bt.z;
  o.w = (z.w - mu) * rstd * gm.w + bt.w;
  *reinterpret_cast<float4*>(out + (size_t)(s * B_ + b) * D_ + (tid << 2)) = o;
}

extern "C" void kernel_launch(void* const* d_in, const int* in_sizes, int n_in,
                              void* d_out, int out_size, void* d_ws, size_t ws_size,
                              hipStream_t stream) {
  const float* q = (const float*)d_in[0];
  const float* k = (const float*)d_in[1];
  const float* v = (const float*)d_in[2];
  const float* sph = (const float*)d_in[3];
  const float* Wq = (const float*)d_in[4];
  const float* Wk = (const float*)d_in[5];
  const float* Wv = (const float*)d_in[6];
  const float* Wo = (const float*)d_in[7];
  const float* gamma = (const float*)d_in[8];
  const float* beta = (const float*)d_in[9];

  float* out = (float*)d_out;                 // [S,B,D]
  float* P = out + (size_t)4 * 1024 * 1024;   // [B,H,S,S]

  char* ws = (char*)d_ws;
  __hip_bfloat16* xq = (__hip_bfloat16*)(ws);                        // 8MB [S*B][D]
  __hip_bfloat16* xk = (__hip_bfloat16*)(ws + ((size_t)8 << 20));    // 8MB
  __hip_bfloat16* xv = (__hip_bfloat16*)(ws + ((size_t)16 << 20));   // 8MB
  __hip_bfloat16* wqb = (__hip_bfloat16*)(ws + ((size_t)24 << 20));  // 2MB
  __hip_bfloat16* wkb = (__hip_bfloat16*)(ws + ((size_t)26 << 20));
  __hip_bfloat16* wvb = (__hip_bfloat16*)(ws + ((size_t)28 << 20));
  __hip_bfloat16* wob = (__hip_bfloat16*)(ws + ((size_t)30 << 20));
  __hip_bfloat16* Qh = (__hip_bfloat16*)(ws + ((size_t)32 << 20));   // 8MB [bh][s][dk]
  __hip_bfloat16* Khb = (__hip_bfloat16*)(ws + ((size_t)40 << 20));  // 8MB [bh][s][dk]
  __hip_bfloat16* VTb = (__hip_bfloat16*)(ws + ((size_t)48 << 20));  // 8MB [bh][dk][s]
  __hip_bfloat16* Ob = (__hip_bfloat16*)(ws + ((size_t)56 << 20));   // 8MB [B][S][D]
  float* Z = (float*)(ws + ((size_t)64 << 20));                      // 16MB [B][S][D]

  const dim3 blk(256);
  k_cvt<<<4096, blk, 0, stream>>>(q, xq, 1048576);
  k_cvt<<<4096, blk, 0, stream>>>(k, xk, 1048576);
  k_cvt<<<4096, blk, 0, stream>>>(v, xv, 1048576);
  k_cvt<<<1024, blk, 0, stream>>>(Wq, wqb, 262144);
  k_cvt<<<1024, blk, 0, stream>>>(Wk, wkb, 262144);
  k_cvt<<<1024, blk, 0, stream>>>(Wv, wvb, 262144);
  k_cvt<<<1024, blk, 0, stream>>>(Wo, wob, 262144);

  k_gemm<0><<<dim3(32, 16), blk, 0, stream>>>(xq, wqb, nullptr, Qh, nullptr);
  k_gemm<0><<<dim3(32, 16), blk, 0, stream>>>(xk, wkb, nullptr, Khb, nullptr);
  k_gemm<1><<<dim3(32, 16), blk, 0, stream>>>(xv, wvb, nullptr, VTb, nullptr);

  k_attn<<<dim3(32, 64), blk, 0, stream>>>(Qh, Khb, VTb, sph, P, Ob);

  k_gemm<2><<<dim3(32, 16), blk, 0, stream>>>(Ob, wob, q, nullptr, Z);
  k_ln<<<4096, blk, 0, stream>>>(Z, gamma, beta, out);
}